// Round 2
// baseline (240.455 us; speedup 1.0000x reference)
//
#include <hip/hip_runtime.h>

// LSTM: B=2048, T=512, INPUT=2, H=32, OUT=1. One wave per batch element.
// Lane j (0..63) owns gate rows j and j+64:
//   lanes 0..31  -> i_j, g_j ; lanes 32..63 -> f_{j-32}, o_{j-32}
// Round 6 = Round 5 with the permlane32_swap result-pair order FLIPPED.
// Empirical finding (R5 absmax 0.275, scaling verified exact): the builtin's
// 2-vector packs {vsrc_new, vdst_new} -> element .y is (low:cross, high:own),
// element .x is (low:own, high:cross).
//  - half-wave gate exchange via v_permlane32_swap_b32 (VALU pipe) instead of
//    __shfl_xor -> ds_bpermute (LGKM), no cndmasks.
//  - log2e folded into W_ih/W_hh/biases; tanh-input doubling folded into the
//    g-row scale; c kept in 2*log2e-scaled form. sigmoid = rcp(1+exp2(-x)).
//  - h epilogue merged: h = fma(2*ov, sigm(c'), -ov).
//  - x read as one b128 per 2 timesteps.

#define BB 2048
#define TT 512
#define HH 32
#define CHUNK 64
#define HROW 33   // FC-history row stride: (lane+u)%32 -> 2-way alias = free

#define LOG2E 1.44269504088896340736f

typedef float v2f __attribute__((ext_vector_type(2)));
typedef float v4f __attribute__((ext_vector_type(4)));
typedef unsigned int v2u __attribute__((ext_vector_type(2)));

__global__ __launch_bounds__(256, 2) void lstm_fused_kernel(
    const float* __restrict__ x,     // [B, T, 2]
    const float* __restrict__ W_ih,  // [128, 2]
    const float* __restrict__ W_hh,  // [128, 32]
    const float* __restrict__ b_ih,  // [128]
    const float* __restrict__ b_hh,  // [128]
    const float* __restrict__ W_fc,  // [1, 32]
    const float* __restrict__ b_fc,  // [1]
    float* __restrict__ out)         // [B, T, 1]
{
    __shared__ float lds_x[4 * TT * 2];              // 16 KB  x staging
    __shared__ float lds_h[4 * CHUNK * HROW];        // 33 KB  FC history
    __shared__ __align__(16) float lds_bc[4][64];    // 1 KB   h broadcast

    const int lane = threadIdx.x & 63;
    const int wv   = threadIdx.x >> 6;
    const int b    = blockIdx.x * 4 + wv;
    const bool low = (lane < 32);

    // ---- stage x[T,2] into LDS, coalesced float4 (wave-private, no barrier) ----
    {
        const float4* xg = (const float4*)(x + (size_t)b * TT * 2);
        float4* xs = (float4*)(lds_x + wv * TT * 2);
        #pragma unroll
        for (int r = 0; r < 4; ++r) xs[r * 64 + lane] = xg[r * 64 + lane];
    }

    // ---- per-lane weights, packed in k-pairs, PRE-SCALED by log2e ----
    // rows rlo (i/f): scale log2e  -> sigmoid = rcp(1+exp2(-g'))
    // rows rhi: low lanes (g): scale 2*log2e (tanh(x)=2*sigm(2x)-1)
    //           high lanes (o): scale log2e
    const int rlo = lane;
    const int rhi = lane + 64;
    const float sl = LOG2E;
    const float sh = low ? 2.0f * LOG2E : LOG2E;

    const v2f wihl = ((const v2f*)W_ih)[rlo] * sl;
    const v2f wihh = ((const v2f*)W_ih)[rhi] * sh;
    const float bl = (b_ih[rlo] + b_hh[rlo]) * sl;
    const float bh = (b_ih[rhi] + b_hh[rhi]) * sh;

    v2f wloq[HH / 2], whiq[HH / 2];
    #pragma unroll
    for (int k = 0; k < HH / 2; ++k) {
        wloq[k] = ((const v2f*)(W_hh + rlo * HH))[k] * sl;
        whiq[k] = ((const v2f*)(W_hh + rhi * HH))[k] * sh;
    }

    // FC weights (wave-uniform -> SGPRs)
    float wfc[HH];
    #pragma unroll
    for (int u = 0; u < HH; ++u) wfc[u] = W_fc[u];
    const float bfc = b_fc[0];

    // hi-gate activation: low lanes produce g' = 2*log2e*tanh(g) directly:
    //   g' = 4*log2e*sigm(2g) - 2*log2e ; high lanes: plain sigmoid(o)
    const float Aa = low ?  4.0f * LOG2E : 1.0f;
    const float Bb = low ? -2.0f * LOG2E : 0.0f;

    float c = 0.0f;   // c' = 2*log2e * c_true

    float* out_b = out + (size_t)b * TT;
    const v4f* xw4 = (const v4f*)(lds_x + wv * TT * 2);
    float* hb  = lds_h + wv * CHUNK * HROW;
    float* bcw = lds_bc[wv];
    const v4f* bcr = (const v4f*)bcw;

    bcw[lane] = 0.0f;   // h_{-1} = 0 (same-wave in-order LDS)

    const v2f binitL = {bl, 0.0f};
    const v2f binitH = {bh, 0.0f};

    #pragma unroll 1
    for (int ch = 0; ch < TT / CHUNK; ++ch) {
        #pragma unroll 1
        for (int uu = 0; uu < CHUNK; uu += 2) {
            // one b128 covers x_t and x_{t+1}
            v4f xq = xw4[(ch * CHUNK + uu) >> 1];

            #pragma unroll
            for (int s = 0; s < 2; ++s) {
                const int u = uu + s;

                // broadcast h_{t-1}: 8 quad reads, all lanes same address
                v4f hq[8];
                #pragma unroll
                for (int q = 0; q < 8; ++q) hq[q] = bcr[q];

                v2f xt = s ? (v2f){xq.z, xq.w} : (v2f){xq.x, xq.y};

                // x-projection + bias (pre-scaled), packed
                v2f aL0 = __builtin_elementwise_fma(xt, wihl, binitL);
                v2f aH0 = __builtin_elementwise_fma(xt, wihh, binitH);
                v2f aL1 = {0.0f, 0.0f};
                v2f aH1 = {0.0f, 0.0f};

                // recurrent dot: 4 chains of 8 pk-FMAs
                #pragma unroll
                for (int k = 0; k < HH / 2; ++k) {
                    v2f hp = (k & 1)
                        ? __builtin_shufflevector(hq[k >> 1], hq[k >> 1], 2, 3)
                        : __builtin_shufflevector(hq[k >> 1], hq[k >> 1], 0, 1);
                    if (k < HH / 4) {
                        aL0 = __builtin_elementwise_fma(hp, wloq[k], aL0);
                        aH0 = __builtin_elementwise_fma(hp, whiq[k], aH0);
                    } else {
                        aL1 = __builtin_elementwise_fma(hp, wloq[k], aL1);
                        aH1 = __builtin_elementwise_fma(hp, whiq[k], aH1);
                    }
                }
                v2f aL = aL0 + aL1;
                v2f aH = aH0 + aH1;
                float glo = aL.x + aL.y;   // log2e-scaled pre-activation
                float ghi = aH.x + aH.y;   // (scaled) pre-activation

                // sigmoid in exp2 space; neg is a free input modifier
                float alo = __builtin_amdgcn_rcpf(1.0f + exp2f(-glo)); // i / f
                float shi = __builtin_amdgcn_rcpf(1.0f + exp2f(-ghi));
                float ahi = fmaf(Aa, shi, Bb);                         // g' / o

                // half-wave exchange via v_permlane32_swap_b32.
                // R6 FLIP: pair order is {vsrc_new, vdst_new}:
                //   .y = (low: cross, high: own)   .x = (low: own, high: cross)
                v2u r1 = __builtin_amdgcn_permlane32_swap(
                    __float_as_uint(alo), __float_as_uint(alo), false, false);
                v2u r2 = __builtin_amdgcn_permlane32_swap(
                    __float_as_uint(ahi), __float_as_uint(ahi), false, false);
                float fv = __uint_as_float(r1.y);   // sigm(f)
                float iv = __uint_as_float(r1.x);   // sigm(i)
                float ov = __uint_as_float(r2.y);   // sigm(o)
                float gv = __uint_as_float(r2.x);   // 2*log2e*tanh(g)

                // c' = f*c' + i*g'   (stays in 2*log2e scale)
                float ig = iv * gv;
                c = fmaf(fv, c, ig);

                // h = o * tanh(c) = fma(2*o, sigm(c'), -o); 2*o off critical path
                float rr  = __builtin_amdgcn_rcpf(1.0f + exp2f(-c));
                float ov2 = ov + ov;
                float hnew = fmaf(ov2, rr, -ov);    // valid on ALL lanes

                // single combined write: low lanes -> broadcast buffer,
                // high lanes -> FC history row u
                float* wr = low ? (bcw + lane) : (hb + u * HROW + (lane - 32));
                *wr = hnew;
            }
        }

        // ---- chunk flush: FC for 64 timesteps, coalesced store ----
        float acc = bfc;
        const float* row = hb + lane * HROW;
        #pragma unroll
        for (int u = 0; u < HH; ++u)
            acc = fmaf(row[u], wfc[u], acc);
        out_b[ch * CHUNK + lane] = acc;
    }
}

extern "C" void kernel_launch(void* const* d_in, const int* in_sizes, int n_in,
                              void* d_out, int out_size, void* d_ws, size_t ws_size,
                              hipStream_t stream) {
    const float* x    = (const float*)d_in[0];
    const float* W_ih = (const float*)d_in[1];
    const float* W_hh = (const float*)d_in[2];
    const float* b_ih = (const float*)d_in[3];
    const float* b_hh = (const float*)d_in[4];
    const float* W_fc = (const float*)d_in[5];
    const float* b_fc = (const float*)d_in[6];
    float* out = (float*)d_out;

    dim3 grid(BB / 4);
    dim3 block(256);
    lstm_fused_kernel<<<grid, block, 0, stream>>>(x, W_ih, W_hh, b_ih, b_hh,
                                                  W_fc, b_fc, out);
}

// Round 3
// 213.168 us; speedup vs baseline: 1.1280x; 1.1280x over previous
//
#include <hip/hip_runtime.h>

// LSTM: B=2048, T=512, INPUT=2, H=32, OUT=1. One wave per batch element.
// Lane j (0..63) owns gate rows j and j+64:
//   lanes 0..31  -> i_j, g_j ; lanes 32..63 -> f_{j-32}, o_{j-32}
// Round 7 = Round 6 with:
//  - __builtin_amdgcn_exp2f (bare v_exp_f32) instead of libm exp2f. The libm
//    call lowers to a denorm-range fixup (~4-5 instrs) without fast-math;
//    that was R6's +15% VALU-cycle regression. Args are range-safe (|x|<~60).
//  - per-step store pointer carried as induction variable (wr += winc) instead
//    of per-step select+address-math; rewound once per chunk.
// Carried from R6:
//  - half-wave gate exchange via v_permlane32_swap_b32 (VALU pipe, no LGKM
//    in the recurrence chain, no cndmasks). Pair order: {vdst_new, vsrc_new}
//    -> .x = (low: own, high: cross), .y = (low: cross, high: own).
//  - log2e folded into W_ih/W_hh/biases; tanh-input doubling folded into the
//    g-row scale; c kept in 2*log2e-scaled form. sigmoid = rcp(1+exp2(-x)).
//  - h epilogue merged: h = fma(2*ov, sigm(c'), -ov).
//  - x read as one b128 per 2 timesteps.

#define BB 2048
#define TT 512
#define HH 32
#define CHUNK 64
#define HROW 33   // FC-history row stride: (lane+u)%32 -> 2-way alias = free

#define LOG2E 1.44269504088896340736f

typedef float v2f __attribute__((ext_vector_type(2)));
typedef float v4f __attribute__((ext_vector_type(4)));
typedef unsigned int v2u __attribute__((ext_vector_type(2)));

__device__ __forceinline__ float sigm2(float xs) {
    // xs is log2e-scaled: returns 1/(1+2^-xs) = sigmoid(xs/log2e)
    return __builtin_amdgcn_rcpf(1.0f + __builtin_amdgcn_exp2f(-xs));
}

__global__ __launch_bounds__(256, 2) void lstm_fused_kernel(
    const float* __restrict__ x,     // [B, T, 2]
    const float* __restrict__ W_ih,  // [128, 2]
    const float* __restrict__ W_hh,  // [128, 32]
    const float* __restrict__ b_ih,  // [128]
    const float* __restrict__ b_hh,  // [128]
    const float* __restrict__ W_fc,  // [1, 32]
    const float* __restrict__ b_fc,  // [1]
    float* __restrict__ out)         // [B, T, 1]
{
    __shared__ float lds_x[4 * TT * 2];              // 16 KB  x staging
    __shared__ float lds_h[4 * CHUNK * HROW];        // 33 KB  FC history
    __shared__ __align__(16) float lds_bc[4][64];    // 1 KB   h broadcast

    const int lane = threadIdx.x & 63;
    const int wv   = threadIdx.x >> 6;
    const int b    = blockIdx.x * 4 + wv;
    const bool low = (lane < 32);

    // ---- stage x[T,2] into LDS, coalesced float4 (wave-private, no barrier) ----
    {
        const float4* xg = (const float4*)(x + (size_t)b * TT * 2);
        float4* xs = (float4*)(lds_x + wv * TT * 2);
        #pragma unroll
        for (int r = 0; r < 4; ++r) xs[r * 64 + lane] = xg[r * 64 + lane];
    }

    // ---- per-lane weights, packed in k-pairs, PRE-SCALED by log2e ----
    // rows rlo (i/f): scale log2e  -> sigmoid = rcp(1+exp2(-g'))
    // rows rhi: low lanes (g): scale 2*log2e (tanh(x)=2*sigm(2x)-1)
    //           high lanes (o): scale log2e
    const int rlo = lane;
    const int rhi = lane + 64;
    const float sl = LOG2E;
    const float sh = low ? 2.0f * LOG2E : LOG2E;

    const v2f wihl = ((const v2f*)W_ih)[rlo] * sl;
    const v2f wihh = ((const v2f*)W_ih)[rhi] * sh;
    const float bl = (b_ih[rlo] + b_hh[rlo]) * sl;
    const float bh = (b_ih[rhi] + b_hh[rhi]) * sh;

    v2f wloq[HH / 2], whiq[HH / 2];
    #pragma unroll
    for (int k = 0; k < HH / 2; ++k) {
        wloq[k] = ((const v2f*)(W_hh + rlo * HH))[k] * sl;
        whiq[k] = ((const v2f*)(W_hh + rhi * HH))[k] * sh;
    }

    // FC weights (wave-uniform -> SGPRs)
    float wfc[HH];
    #pragma unroll
    for (int u = 0; u < HH; ++u) wfc[u] = W_fc[u];
    const float bfc = b_fc[0];

    // hi-gate activation: low lanes produce g' = 2*log2e*tanh(g) directly:
    //   g' = 4*log2e*sigm(2g) - 2*log2e ; high lanes: plain sigmoid(o)
    const float Aa = low ?  4.0f * LOG2E : 1.0f;
    const float Bb = low ? -2.0f * LOG2E : 0.0f;

    float c = 0.0f;   // c' = 2*log2e * c_true

    float* out_b = out + (size_t)b * TT;
    const v4f* xw4 = (const v4f*)(lds_x + wv * TT * 2);
    float* hb  = lds_h + wv * CHUNK * HROW;
    float* bcw = lds_bc[wv];
    const v4f* bcr = (const v4f*)bcw;

    bcw[lane] = 0.0f;   // h_{-1} = 0 (same-wave in-order LDS)

    const v2f binitL = {bl, 0.0f};
    const v2f binitH = {bh, 0.0f};

    // per-lane store pointer as induction variable:
    // low lanes: fixed broadcast slot; high lanes: walk FC-history rows
    float* wr = low ? (bcw + lane) : (hb + (lane - 32));
    const int winc = low ? 0 : HROW;

    #pragma unroll 1
    for (int ch = 0; ch < TT / CHUNK; ++ch) {
        #pragma unroll 1
        for (int uu = 0; uu < CHUNK; uu += 2) {
            // one b128 covers x_t and x_{t+1}
            v4f xq = xw4[(ch * CHUNK + uu) >> 1];

            #pragma unroll
            for (int s = 0; s < 2; ++s) {
                // broadcast h_{t-1}: 8 quad reads, all lanes same address
                v4f hq[8];
                #pragma unroll
                for (int q = 0; q < 8; ++q) hq[q] = bcr[q];

                v2f xt = s ? (v2f){xq.z, xq.w} : (v2f){xq.x, xq.y};

                // x-projection + bias (pre-scaled), packed
                v2f aL0 = __builtin_elementwise_fma(xt, wihl, binitL);
                v2f aH0 = __builtin_elementwise_fma(xt, wihh, binitH);
                v2f aL1 = {0.0f, 0.0f};
                v2f aH1 = {0.0f, 0.0f};

                // recurrent dot: 4 chains of 8 pk-FMAs
                #pragma unroll
                for (int k = 0; k < HH / 2; ++k) {
                    v2f hp = (k & 1)
                        ? __builtin_shufflevector(hq[k >> 1], hq[k >> 1], 2, 3)
                        : __builtin_shufflevector(hq[k >> 1], hq[k >> 1], 0, 1);
                    if (k < HH / 4) {
                        aL0 = __builtin_elementwise_fma(hp, wloq[k], aL0);
                        aH0 = __builtin_elementwise_fma(hp, whiq[k], aH0);
                    } else {
                        aL1 = __builtin_elementwise_fma(hp, wloq[k], aL1);
                        aH1 = __builtin_elementwise_fma(hp, whiq[k], aH1);
                    }
                }
                v2f aL = aL0 + aL1;
                v2f aH = aH0 + aH1;
                float glo = aL.x + aL.y;   // log2e-scaled pre-activation
                float ghi = aH.x + aH.y;   // (scaled) pre-activation

                // sigmoid via bare v_exp_f32 (neg = free input modifier)
                float alo = sigm2(glo);                 // i / f
                float shi = sigm2(ghi);
                float ahi = fmaf(Aa, shi, Bb);          // g' / o

                // half-wave exchange via v_permlane32_swap_b32.
                // pair = {vdst_new, vsrc_new}:
                //   .y = (low: cross, high: own)   .x = (low: own, high: cross)
                v2u r1 = __builtin_amdgcn_permlane32_swap(
                    __float_as_uint(alo), __float_as_uint(alo), false, false);
                v2u r2 = __builtin_amdgcn_permlane32_swap(
                    __float_as_uint(ahi), __float_as_uint(ahi), false, false);
                float fv = __uint_as_float(r1.y);   // sigm(f)
                float iv = __uint_as_float(r1.x);   // sigm(i)
                float ov = __uint_as_float(r2.y);   // sigm(o)
                float gv = __uint_as_float(r2.x);   // 2*log2e*tanh(g)

                // c' = f*c' + i*g'   (stays in 2*log2e scale)
                float ig = iv * gv;
                c = fmaf(fv, c, ig);

                // h = o * tanh(c) = fma(2*o, sigm(c'), -o); 2*o off critical path
                float rr  = sigm2(c);
                float ov2 = ov + ov;
                float hnew = fmaf(ov2, rr, -ov);    // valid on ALL lanes

                // single combined write: low lanes -> broadcast slot,
                // high lanes -> FC history row u (pointer walks by HROW)
                *wr = hnew;
                wr += winc;
            }
        }

        // rewind high-lane history pointer for next chunk (low: no-op)
        wr -= winc * CHUNK;

        // ---- chunk flush: FC for 64 timesteps, coalesced store ----
        float acc = bfc;
        const float* row = hb + lane * HROW;
        #pragma unroll
        for (int u = 0; u < HH; ++u)
            acc = fmaf(row[u], wfc[u], acc);
        out_b[ch * CHUNK + lane] = acc;
    }
}

extern "C" void kernel_launch(void* const* d_in, const int* in_sizes, int n_in,
                              void* d_out, int out_size, void* d_ws, size_t ws_size,
                              hipStream_t stream) {
    const float* x    = (const float*)d_in[0];
    const float* W_ih = (const float*)d_in[1];
    const float* W_hh = (const float*)d_in[2];
    const float* b_ih = (const float*)d_in[3];
    const float* b_hh = (const float*)d_in[4];
    const float* W_fc = (const float*)d_in[5];
    const float* b_fc = (const float*)d_in[6];
    float* out = (float*)d_out;

    dim3 grid(BB / 4);
    dim3 block(256);
    lstm_fused_kernel<<<grid, block, 0, stream>>>(x, W_ih, W_hh, b_ih, b_hh,
                                                  W_fc, b_fc, out);
}